// Round 6
// baseline (91.678 us; speedup 1.0000x reference)
//
#include <hip/hip_runtime.h>

// PlaylistEmbedding: out[b,:] = sum_n values[b,n] * w[indices[b,n],:] + bias
// B=16384, NNZ=200, EMB=32, fp32 in/out, indices int32.
//
// R5 result: random-128B-line L2-miss path saturates at ~3.5 TB/s regardless
// of MLP/occupancy -> reduce miss traffic instead:
//  (1) bf16-pack w into d_ws (RNE) -> table 10.4->5.2 MB, 64B/row gathers.
//  (2) L2 vocab tiling: per row, bucket 200 (idx,val) into 2 tiles
//      (SPLIT=40960, ~2.6MB each, fits 4MB L2/XCD) via ballot-scan into a
//      two-sided per-wave LDS array (tile0 grows from slot 0, tile1 from
//      slot 199 down -> exactly 200 slots, no overflow possible). Then
//      process in q-order (tile0 then tile1) as a STATIC 4-superstep stream
//      (64 entries each, 8 per s-group) with the proven R5 asm A/B pipeline:
//      8 global_load_dwordx2 in flight through every FMA block, hand-counted
//      s_waitcnt vmcnt(8)/(0) + sched_barrier(0).
// lane = s*8 + c: c in [0,8) -> 4 consecutive embedding dims (8B bf16);
// s in [0,8) -> 8 parallel entry streams; shfl_xor reduce over s.
// Fallback: if ws_size < 5.2MB, run the R4/R5 fp32 kernel.

constexpr int NNZ = 200;
constexpr int THREADS = 256;
constexpr int VOCAB = 81616;
constexpr int EMB = 32;
constexpr int SPLIT = 40960;            // tile0: [0,40960) = 2.5MB bf16
constexpr int ROWS_PER_WAVE = 4;        // 16 rows/block, grid = 1024
constexpr size_t WBF_BYTES = (size_t)VOCAB * EMB * 2;  // 5,223,424

// ---------------- prologue: w fp32 -> bf16 (RNE) into d_ws ----------------
__global__ __launch_bounds__(256) void convert_w_bf16(
    const float* __restrict__ w, unsigned short* __restrict__ o, int n)
{
    int i = blockIdx.x * blockDim.x + threadIdx.x;   // octet index
    if (i * 8 >= n) return;
    const uint4 a = ((const uint4*)w)[i * 2 + 0];
    const uint4 b = ((const uint4*)w)[i * 2 + 1];
    auto cv = [](unsigned u) -> unsigned {
        return (u + 0x7FFFu + ((u >> 16) & 1u)) >> 16;   // RNE to bf16
    };
    uint4 p;
    p.x = cv(a.x) | (cv(a.y) << 16);
    p.y = cv(a.z) | (cv(a.w) << 16);
    p.z = cv(b.x) | (cv(b.y) << 16);
    p.w = cv(b.z) | (cv(b.w) << 16);
    ((uint4*)o)[i] = p;
}

// ---------------- main kernel: bf16 gathers, L2-tiled ----------------
__global__ __launch_bounds__(THREADS, 4) void pe_bf16_tiled(
    const int* __restrict__ indices,
    const float* __restrict__ values,
    const unsigned short* __restrict__ wb,   // [VOCAB][32] bf16
    const float* __restrict__ bias,
    float* __restrict__ out)
{
    __shared__ unsigned long long bkt[4][NNZ];   // per-wave: lo32=idx, hi32=val bits

    const int tid  = threadIdx.x;
    const int wv   = tid >> 6;
    const int lane = tid & 63;
    const int s    = lane >> 3;          // 0..7 entry stream
    const int c    = lane & 7;           // 0..7 -> dims 4c..4c+3
    unsigned long long* __restrict__ B = bkt[wv];

    for (int rr = 0; rr < ROWS_PER_WAVE; ++rr) {
        const int row = blockIdx.x * (4 * ROWS_PER_WAVE) + wv * ROWS_PER_WAVE + rr;
        const int*   __restrict__ ri = indices + (size_t)row * NNZ;
        const float* __restrict__ rv = values  + (size_t)row * NNZ;

        // ---- build two-sided bucket (ballot scan, no atomics) ----
        int left = 0, right = 0;
#pragma unroll
        for (int j = 0; j < 4; ++j) {
            const int n = j * 64 + lane;
            const bool valid = (n < NNZ);
            int iv = 0; float vvf = 0.f;
            if (valid) {
                iv  = __builtin_nontemporal_load(ri + n);
                vvf = __builtin_nontemporal_load(rv + n);
            }
            const bool b0 = valid && (iv <  SPLIT);
            const bool b1 = valid && (iv >= SPLIT);
            const unsigned long long m0 = __ballot(b0);
            const unsigned long long m1 = __ballot(b1);
            const int bel0 = __builtin_amdgcn_mbcnt_hi(
                (unsigned)(m0 >> 32), __builtin_amdgcn_mbcnt_lo((unsigned)m0, 0));
            const int bel1 = __builtin_amdgcn_mbcnt_hi(
                (unsigned)(m1 >> 32), __builtin_amdgcn_mbcnt_lo((unsigned)m1, 0));
            if (valid) {
                const int slot = b0 ? (left + bel0) : (NNZ - 1 - (right + bel1));
                B[slot] = ((unsigned long long)__float_as_uint(vvf) << 32) | (unsigned)iv;
            }
            left  += __popcll(m0);
            right += __popcll(m1);
        }
        const int cnt0 = left;
        const int gap  = NNZ - right - cnt0;   // slot(q) = q < cnt0 ? q : q+gap

        // Drain ordinary vmem so asm vmcnt counts are exact.
        asm volatile("s_waitcnt vmcnt(0)" ::: "memory");
        __builtin_amdgcn_sched_barrier(0);

        float ax = 0.f, ay = 0.f, az = 0.f, aw = 0.f;
        uint2 GA[8], GB[8];
        float VA[8], VB[8];

#define ISSUE(K, G, V) do {                                                    \
    _Pragma("unroll")                                                          \
    for (int e = 0; e < 8; ++e) {                                              \
        const int q = (K) * 64 + s * 8 + e;                                    \
        const bool tval = ((K) < 3) || (q < NNZ);                              \
        int sl = (q < cnt0) ? q : q + gap;                                     \
        if (!tval) sl = 0;                                                     \
        const unsigned long long ent = B[sl];                                  \
        const int iv = (int)(unsigned)ent;                                     \
        V[e] = tval ? __uint_as_float((unsigned)(ent >> 32)) : 0.f;            \
        const unsigned short* a_ = wb + ((size_t)iv * 32 + c * 4);             \
        asm volatile("global_load_dwordx2 %0, %1, off"                         \
                     : "=v"(G[e]) : "v"(a_));                                  \
    }                                                                          \
} while (0)

#define FMA8(G, V) do {                                                        \
    _Pragma("unroll")                                                          \
    for (int e = 0; e < 8; ++e) {                                              \
        const float f0 = __uint_as_float(G[e].x << 16);                        \
        const float f1 = __uint_as_float(G[e].x & 0xFFFF0000u);                \
        const float f2 = __uint_as_float(G[e].y << 16);                        \
        const float f3 = __uint_as_float(G[e].y & 0xFFFF0000u);                \
        ax += V[e] * f0; ay += V[e] * f1;                                      \
        az += V[e] * f2; aw += V[e] * f3;                                      \
    }                                                                          \
} while (0)

#define WAITV(N) do {                                                          \
    asm volatile("s_waitcnt vmcnt(" #N ")" ::: "memory");                      \
    __builtin_amdgcn_sched_barrier(0);                                         \
} while (0)

        // Static 4-superstep A/B pipeline: 8-16 dwordx2 in flight.
        ISSUE(0, GA, VA);
        ISSUE(1, GB, VB);
        WAITV(8);  FMA8(GA, VA);
        ISSUE(2, GA, VA);
        WAITV(8);  FMA8(GB, VB);
        ISSUE(3, GB, VB);
        WAITV(8);  FMA8(GA, VA);
        WAITV(0);  FMA8(GB, VB);

#undef ISSUE
#undef FMA8
#undef WAITV

        asm volatile("" ::: "memory");

        // reduce over the 8 s-streams
#pragma unroll
        for (int m = 8; m <= 32; m <<= 1) {
            ax += __shfl_xor(ax, m);
            ay += __shfl_xor(ay, m);
            az += __shfl_xor(az, m);
            aw += __shfl_xor(aw, m);
        }
        if (s == 0) {
            const float4 b4 = ((const float4*)bias)[c];
            float4 o;
            o.x = ax + b4.x; o.y = ay + b4.y;
            o.z = az + b4.z; o.w = aw + b4.w;
            ((float4*)out)[(size_t)row * 8 + c] = o;
        }
    }
}

// ---------------- fallback (R5 kernel, fp32 direct) ----------------
__global__ __launch_bounds__(THREADS, 4) void pe_fp32_direct(
    const int* __restrict__ indices, const float* __restrict__ values,
    const float* __restrict__ w, const float* __restrict__ bias,
    float* __restrict__ out)
{
    const int tid  = threadIdx.x;
    const int wave = tid >> 6;
    const int lane = tid & 63;
    const int s    = lane >> 3;
    const int c    = lane & 7;
    const int row  = blockIdx.x * 4 + wave;

    const int*   __restrict__ ri = indices + (size_t)row * NNZ;
    const float* __restrict__ rv = values  + (size_t)row * NNZ;
    const float4* __restrict__ w4 = (const float4*)w;

    float ax = 0.f, ay = 0.f, az = 0.f, aw = 0.f;
#pragma unroll 5
    for (int k = 0; k < NNZ / 8; ++k) {
        const int n = s + (k << 3);
        const int   u = ri[n];
        const float v = rv[n];
        const float4 wv = w4[(size_t)u * 8 + c];
        ax += v * wv.x; ay += v * wv.y; az += v * wv.z; aw += v * wv.w;
    }
#pragma unroll
    for (int m = 8; m <= 32; m <<= 1) {
        ax += __shfl_xor(ax, m); ay += __shfl_xor(ay, m);
        az += __shfl_xor(az, m); aw += __shfl_xor(aw, m);
    }
    if (s == 0) {
        const float4 b4 = ((const float4*)bias)[c];
        float4 o;
        o.x = ax + b4.x; o.y = ay + b4.y; o.z = az + b4.z; o.w = aw + b4.w;
        ((float4*)out)[(size_t)row * 8 + c] = o;
    }
}

extern "C" void kernel_launch(void* const* d_in, const int* in_sizes, int n_in,
                              void* d_out, int out_size, void* d_ws, size_t ws_size,
                              hipStream_t stream) {
    const int*   indices = (const int*)d_in[0];    // [16384, 200]
    const float* values  = (const float*)d_in[1];  // [16384, 200]
    const float* w       = (const float*)d_in[2];  // [81616, 32]
    const float* bias    = (const float*)d_in[3];  // [32]
    float* out = (float*)d_out;                    // [16384, 32]

    const int B = in_sizes[0] / NNZ;               // 16384

    if (ws_size >= WBF_BYTES) {
        unsigned short* wb = (unsigned short*)d_ws;
        const int nelem = VOCAB * EMB;             // 2,611,712
        const int cgrid = (nelem / 8 + 255) / 256; // 1276
        convert_w_bf16<<<cgrid, 256, 0, stream>>>(w, wb, nelem);

        const int grid = B / (4 * ROWS_PER_WAVE);  // 1024
        pe_bf16_tiled<<<grid, THREADS, 0, stream>>>(indices, values, wb, bias, out);
    } else {
        pe_fp32_direct<<<B / 4, THREADS, 0, stream>>>(indices, values, w, bias, out);
    }
}

// Round 7
// 80.158 us; speedup vs baseline: 1.1437x; 1.1437x over previous
//
#include <hip/hip_runtime.h>

// PlaylistEmbedding: out[b,:] = sum_n values[b,n] * w[indices[b,n],:] + bias
// B=16384, NNZ=200, EMB=32, fp32 in/out, indices int32.
//
// R5: direct random gathers saturate the L2-miss/fabric path at ~3.5 TB/s
// (145 MB FETCH @ 43 us) regardless of occupancy/MLP. R6: bf16 numerics OK
// (absmax 0.016 << 0.067) but per-row tiling + asm pipeline caused scratch
// spills (113 MB writes) and no phase alignment.
//
// R7: grid-level vocab tiling, maximally simple kernels.
//   prologue: w fp32 -> bf16 RNE into d_ws (table 10.4 -> 5.2 MB, 64B/row).
//   pass 0: all rows, gather only idx in [0, 40808)      (tile = 2.61 MB,
//   pass 1: all rows, gather only idx in [40808, 81616)   fits 4MB L2/XCD),
//           out = pass0 acc + bias; pass1 does out += acc.
// Tile membership is uniform within each 8-lane c-group (same u), so the
// branch is clean exec-masking and masked gathers issue no L2 request.
// Structure per pass = the proven R2 kernel (wave per row, lane = s*8+c,
// compiler-scheduled, no LDS, no asm -> no spills).

constexpr int NNZ = 200;
constexpr int THREADS = 256;
constexpr int VOCAB = 81616;
constexpr int EMB = 32;
constexpr int SPLIT = VOCAB / 2;                       // 40808
constexpr size_t WBF_BYTES = (size_t)VOCAB * EMB * 2;  // 5,223,424

// ---------------- prologue: w fp32 -> bf16 (RNE) into d_ws ----------------
__global__ __launch_bounds__(256) void convert_w_bf16(
    const float* __restrict__ w, unsigned short* __restrict__ o, int n)
{
    int i = blockIdx.x * blockDim.x + threadIdx.x;   // octet index
    if (i * 8 >= n) return;
    const uint4 a = ((const uint4*)w)[i * 2 + 0];
    const uint4 b = ((const uint4*)w)[i * 2 + 1];
    auto cv = [](unsigned u) -> unsigned {
        return (u + 0x7FFFu + ((u >> 16) & 1u)) >> 16;   // RNE to bf16
    };
    uint4 p;
    p.x = cv(a.x) | (cv(a.y) << 16);
    p.y = cv(a.z) | (cv(a.w) << 16);
    p.z = cv(b.x) | (cv(b.y) << 16);
    p.w = cv(b.z) | (cv(b.w) << 16);
    ((uint4*)o)[i] = p;
}

// ---------------- per-tile pass ----------------
template <int PASS>
__global__ __launch_bounds__(THREADS) void pe_pass(
    const int* __restrict__ indices,     // [B, NNZ]
    const float* __restrict__ values,    // [B, NNZ]
    const uint2* __restrict__ wb2,       // [VOCAB][8] x uint2 (bf16 pairs)
    const float* __restrict__ bias,      // [32]
    float* __restrict__ out)             // [B, 32]
{
    const int tid  = threadIdx.x;
    const int wave = tid >> 6;
    const int lane = tid & 63;
    const int s    = lane >> 3;          // 0..7 nnz stream
    const int c    = lane & 7;           // 0..7 -> dims 4c..4c+3
    const int row  = blockIdx.x * 4 + wave;

    const int*   __restrict__ ri = indices + (size_t)row * NNZ;
    const float* __restrict__ rv = values  + (size_t)row * NNZ;

    constexpr int LO = (PASS == 0) ? 0 : SPLIT;
    constexpr int HI = (PASS == 0) ? SPLIT : VOCAB;

    float ax = 0.f, ay = 0.f, az = 0.f, aw = 0.f;

#pragma unroll 5
    for (int k = 0; k < NNZ / 8; ++k) {
        const int n = s + (k << 3);
        const int u = ri[n];                       // uniform in c-group
        if (u >= LO && u < HI) {
            const float v = rv[n];
            const uint2 g = wb2[(size_t)u * 8 + c]; // 8B of the 64B bf16 row
            ax += v * __uint_as_float(g.x << 16);
            ay += v * __uint_as_float(g.x & 0xFFFF0000u);
            az += v * __uint_as_float(g.y << 16);
            aw += v * __uint_as_float(g.y & 0xFFFF0000u);
        }
    }

    // reduce over the 8 s-streams (lane bits 3..5)
#pragma unroll
    for (int m = 8; m <= 32; m <<= 1) {
        ax += __shfl_xor(ax, m);
        ay += __shfl_xor(ay, m);
        az += __shfl_xor(az, m);
        aw += __shfl_xor(aw, m);
    }

    if (s == 0) {
        float4 o;
        if (PASS == 0) {
            const float4 b4 = ((const float4*)bias)[c];
            o.x = ax + b4.x; o.y = ay + b4.y;
            o.z = az + b4.z; o.w = aw + b4.w;
        } else {
            const float4 prev = ((const float4*)out)[(size_t)row * 8 + c];
            o.x = ax + prev.x; o.y = ay + prev.y;
            o.z = az + prev.z; o.w = aw + prev.w;
        }
        ((float4*)out)[(size_t)row * 8 + c] = o;
    }
}

// ---------------- fallback: R5 fp32 direct ----------------
__global__ __launch_bounds__(THREADS) void pe_fp32_direct(
    const int* __restrict__ indices, const float* __restrict__ values,
    const float* __restrict__ w, const float* __restrict__ bias,
    float* __restrict__ out)
{
    const int tid  = threadIdx.x;
    const int wave = tid >> 6;
    const int lane = tid & 63;
    const int s    = lane >> 3;
    const int c    = lane & 7;
    const int row  = blockIdx.x * 4 + wave;

    const int*   __restrict__ ri = indices + (size_t)row * NNZ;
    const float* __restrict__ rv = values  + (size_t)row * NNZ;
    const float4* __restrict__ w4 = (const float4*)w;

    float ax = 0.f, ay = 0.f, az = 0.f, aw = 0.f;
#pragma unroll 5
    for (int k = 0; k < NNZ / 8; ++k) {
        const int n = s + (k << 3);
        const int   u = ri[n];
        const float v = rv[n];
        const float4 wv = w4[(size_t)u * 8 + c];
        ax += v * wv.x; ay += v * wv.y; az += v * wv.z; aw += v * wv.w;
    }
#pragma unroll
    for (int m = 8; m <= 32; m <<= 1) {
        ax += __shfl_xor(ax, m); ay += __shfl_xor(ay, m);
        az += __shfl_xor(az, m); aw += __shfl_xor(aw, m);
    }
    if (s == 0) {
        const float4 b4 = ((const float4*)bias)[c];
        float4 o;
        o.x = ax + b4.x; o.y = ay + b4.y; o.z = az + b4.z; o.w = aw + b4.w;
        ((float4*)out)[(size_t)row * 8 + c] = o;
    }
}

extern "C" void kernel_launch(void* const* d_in, const int* in_sizes, int n_in,
                              void* d_out, int out_size, void* d_ws, size_t ws_size,
                              hipStream_t stream) {
    const int*   indices = (const int*)d_in[0];    // [16384, 200]
    const float* values  = (const float*)d_in[1];  // [16384, 200]
    const float* w       = (const float*)d_in[2];  // [81616, 32]
    const float* bias    = (const float*)d_in[3];  // [32]
    float* out = (float*)d_out;                    // [16384, 32]

    const int B = in_sizes[0] / NNZ;               // 16384
    const int grid = B / 4;                        // 4096 blocks, 4 rows each

    if (ws_size >= WBF_BYTES) {
        unsigned short* wb = (unsigned short*)d_ws;
        const int nelem = VOCAB * EMB;             // 2,611,712
        const int cgrid = (nelem / 8 + 255) / 256; // 1276
        convert_w_bf16<<<cgrid, 256, 0, stream>>>(w, wb, nelem);

        const uint2* wb2 = (const uint2*)d_ws;
        pe_pass<0><<<grid, THREADS, 0, stream>>>(indices, values, wb2, bias, out);
        pe_pass<1><<<grid, THREADS, 0, stream>>>(indices, values, wb2, bias, out);
    } else {
        pe_fp32_direct<<<grid, THREADS, 0, stream>>>(indices, values, w, bias, out);
    }
}

// Round 9
// 65.357 us; speedup vs baseline: 1.4027x; 1.2265x over previous
//
#include <hip/hip_runtime.h>

// PlaylistEmbedding: out[b,:] = sum_n values[b,n] * w[indices[b,n],:] + bias
// B=16384, NNZ=200, EMB=32, fp32 in/out, indices int32.
//
// Evidence so far:
//  R5: direct fp32 gathers = fabric-path bound, ~3.5 TB/s ceiling (145 MB @43us),
//      MLP/occupancy don't help. Forced-asm pipeline compiles + verifies.
//  R7: bf16 table (absmax 0.016 ok) + grid-level vocab tiling kills the traffic
//      (FETCH 25 MB/pass) but compiler collapses to VGPR=12 -> ~1 gather in
//      flight -> L2-HIT-LATENCY bound, 46 us/pass.
//  R8/R9 = R7 tiling + R5 forced pipeline (3-deep, 8+ dwordx2 in flight), with
//      the tile test folded into the preload (clamp addr to LO, zero value) so
//      every gather is in-tile (L2-resident) and the pipeline stays static.
//      idx/val streamed with scalar nontemporal loads (the builtin rejects
//      HIP vector-type pointers -- R8 compile failure).
//
// lane = s*8 + c: s in [0,8) = nnz stream, c in [0,8) = 4 embedding dims
// (8B bf16). Stage k covers n = 32k + 4s + {0..3}; stage 6 = tail (s<2).

constexpr int NNZ = 200;
constexpr int THREADS = 256;
constexpr int VOCAB = 81616;
constexpr int EMB = 32;
constexpr int SPLIT = VOCAB / 2;                       // 40808
constexpr size_t WBF_BYTES = (size_t)VOCAB * EMB * 2;  // 5,223,424

// ---------------- prologue: w fp32 -> bf16 (RNE) into d_ws ----------------
__global__ __launch_bounds__(256) void convert_w_bf16(
    const float* __restrict__ w, unsigned short* __restrict__ o, int n)
{
    int i = blockIdx.x * blockDim.x + threadIdx.x;   // octet index
    if (i * 8 >= n) return;
    const uint4 a = ((const uint4*)w)[i * 2 + 0];
    const uint4 b = ((const uint4*)w)[i * 2 + 1];
    auto cv = [](unsigned u) -> unsigned {
        return (u + 0x7FFFu + ((u >> 16) & 1u)) >> 16;   // RNE to bf16
    };
    uint4 p;
    p.x = cv(a.x) | (cv(a.y) << 16);
    p.y = cv(a.z) | (cv(a.w) << 16);
    p.z = cv(b.x) | (cv(b.y) << 16);
    p.w = cv(b.z) | (cv(b.w) << 16);
    ((uint4*)o)[i] = p;
}

// ---------------- per-tile pass: tiled + forced 3-deep pipeline ----------------
template <int PASS>
__global__ __launch_bounds__(THREADS, 4) void pe_pass(
    const int* __restrict__ indices,     // [B, NNZ]
    const float* __restrict__ values,    // [B, NNZ]
    const unsigned short* __restrict__ wb,  // [VOCAB][32] bf16
    const float* __restrict__ bias,      // [32]
    float* __restrict__ out)             // [B, 32]
{
    const int tid  = threadIdx.x;
    const int wave = tid >> 6;
    const int lane = tid & 63;
    const int s    = lane >> 3;          // 0..7
    const int c    = lane & 7;           // 0..7
    const int row  = blockIdx.x * 4 + wave;

    const int*   __restrict__ ri = indices + (size_t)row * NNZ;
    const float* __restrict__ rv = values  + (size_t)row * NNZ;

    constexpr int LO = (PASS == 0) ? 0 : SPLIT;
    constexpr int HI = (PASS == 0) ? SPLIT : VOCAB;

    // ---- Preload + tile-mask all indices/values (scalar nontemporal) ----
    int4   id[7];
    float4 vl[7];
#pragma unroll
    for (int k = 0; k < 7; ++k) {
        const int off = (k < 6) ? (32 * k + 4 * s)
                                : (192 + ((s < 2) ? 4 * s : 0));  // tail clamp
        id[k].x = __builtin_nontemporal_load(ri + off + 0);
        id[k].y = __builtin_nontemporal_load(ri + off + 1);
        id[k].z = __builtin_nontemporal_load(ri + off + 2);
        id[k].w = __builtin_nontemporal_load(ri + off + 3);
        float4 t;
        t.x = __builtin_nontemporal_load(rv + off + 0);
        t.y = __builtin_nontemporal_load(rv + off + 1);
        t.z = __builtin_nontemporal_load(rv + off + 2);
        t.w = __builtin_nontemporal_load(rv + off + 3);
        if (k == 6 && s >= 2) { t.x = 0.f; t.y = 0.f; t.z = 0.f; t.w = 0.f; }
        // tile mask: out-of-tile -> clamp address into tile, zero the value
        if (id[k].x < LO || id[k].x >= HI) { id[k].x = LO; t.x = 0.f; }
        if (id[k].y < LO || id[k].y >= HI) { id[k].y = LO; t.y = 0.f; }
        if (id[k].z < LO || id[k].z >= HI) { id[k].z = LO; t.z = 0.f; }
        if (id[k].w < LO || id[k].w >= HI) { id[k].w = LO; t.w = 0.f; }
        vl[k] = t;
    }

    // Drain ALL ordinary vmem so the asm pipeline's vmcnt counts are exact.
    asm volatile("s_waitcnt vmcnt(0)" ::: "memory");
    __builtin_amdgcn_sched_barrier(0);

    uint2 A0, A1, A2, A3, B0, B1, B2, B3, C0, C1, C2, C3;
    float ax = 0.f, ay = 0.f, az = 0.f, aw = 0.f;

#define GATHER(G0, G1, G2, G3, K) do {                                         \
    const unsigned short* a0_ = wb + ((size_t)id[K].x * 32 + c * 4);           \
    const unsigned short* a1_ = wb + ((size_t)id[K].y * 32 + c * 4);           \
    const unsigned short* a2_ = wb + ((size_t)id[K].z * 32 + c * 4);           \
    const unsigned short* a3_ = wb + ((size_t)id[K].w * 32 + c * 4);           \
    asm volatile("global_load_dwordx2 %0, %1, off" : "=v"(G0) : "v"(a0_));     \
    asm volatile("global_load_dwordx2 %0, %1, off" : "=v"(G1) : "v"(a1_));     \
    asm volatile("global_load_dwordx2 %0, %1, off" : "=v"(G2) : "v"(a2_));     \
    asm volatile("global_load_dwordx2 %0, %1, off" : "=v"(G3) : "v"(a3_));     \
} while (0)

#define FMAS(G0, G1, G2, G3, K) do {                                           \
    const float4 v_ = vl[K];                                                   \
    ax += v_.x * __uint_as_float(G0.x << 16);                                  \
    ay += v_.x * __uint_as_float(G0.x & 0xFFFF0000u);                          \
    az += v_.x * __uint_as_float(G0.y << 16);                                  \
    aw += v_.x * __uint_as_float(G0.y & 0xFFFF0000u);                          \
    ax += v_.y * __uint_as_float(G1.x << 16);                                  \
    ay += v_.y * __uint_as_float(G1.x & 0xFFFF0000u);                          \
    az += v_.y * __uint_as_float(G1.y << 16);                                  \
    aw += v_.y * __uint_as_float(G1.y & 0xFFFF0000u);                          \
    ax += v_.z * __uint_as_float(G2.x << 16);                                  \
    ay += v_.z * __uint_as_float(G2.x & 0xFFFF0000u);                          \
    az += v_.z * __uint_as_float(G2.y << 16);                                  \
    aw += v_.z * __uint_as_float(G2.y & 0xFFFF0000u);                          \
    ax += v_.w * __uint_as_float(G3.x << 16);                                  \
    ay += v_.w * __uint_as_float(G3.x & 0xFFFF0000u);                          \
    az += v_.w * __uint_as_float(G3.y << 16);                                  \
    aw += v_.w * __uint_as_float(G3.y & 0xFFFF0000u);                          \
} while (0)

#define WAITV(N) do {                                                          \
    asm volatile("s_waitcnt vmcnt(" #N ")" ::: "memory");                      \
    __builtin_amdgcn_sched_barrier(0);                                         \
} while (0)

    // 3-deep pipeline: >=8 gathers in flight through every FMA block.
    GATHER(A0, A1, A2, A3, 0);
    GATHER(B0, B1, B2, B3, 1);
    GATHER(C0, C1, C2, C3, 2);
    WAITV(8); FMAS(A0, A1, A2, A3, 0); GATHER(A0, A1, A2, A3, 3);
    WAITV(8); FMAS(B0, B1, B2, B3, 1); GATHER(B0, B1, B2, B3, 4);
    WAITV(8); FMAS(C0, C1, C2, C3, 2); GATHER(C0, C1, C2, C3, 5);
    WAITV(8); FMAS(A0, A1, A2, A3, 3); GATHER(A0, A1, A2, A3, 6);
    WAITV(8); FMAS(B0, B1, B2, B3, 4);
    WAITV(4); FMAS(C0, C1, C2, C3, 5);
    WAITV(0); FMAS(A0, A1, A2, A3, 6);

#undef GATHER
#undef FMAS
#undef WAITV

    asm volatile("" ::: "memory");

    // reduce over the 8 s-streams (lane bits 3..5)
#pragma unroll
    for (int m = 8; m <= 32; m <<= 1) {
        ax += __shfl_xor(ax, m);
        ay += __shfl_xor(ay, m);
        az += __shfl_xor(az, m);
        aw += __shfl_xor(aw, m);
    }

    if (s == 0) {
        float4 o;
        if (PASS == 0) {
            const float4 b4 = ((const float4*)bias)[c];
            o.x = ax + b4.x; o.y = ay + b4.y;
            o.z = az + b4.z; o.w = aw + b4.w;
        } else {
            const float4 prev = ((const float4*)out)[(size_t)row * 8 + c];
            o.x = ax + prev.x; o.y = ay + prev.y;
            o.z = az + prev.z; o.w = aw + prev.w;
        }
        float* po = (float*)out + ((size_t)row * 8 + c) * 4;
        __builtin_nontemporal_store(o.x, po + 0);
        __builtin_nontemporal_store(o.y, po + 1);
        __builtin_nontemporal_store(o.z, po + 2);
        __builtin_nontemporal_store(o.w, po + 3);
    }
}

// ---------------- fallback: fp32 direct (R2 structure) ----------------
__global__ __launch_bounds__(THREADS) void pe_fp32_direct(
    const int* __restrict__ indices, const float* __restrict__ values,
    const float* __restrict__ w, const float* __restrict__ bias,
    float* __restrict__ out)
{
    const int tid  = threadIdx.x;
    const int wave = tid >> 6;
    const int lane = tid & 63;
    const int s    = lane >> 3;
    const int c    = lane & 7;
    const int row  = blockIdx.x * 4 + wave;

    const int*   __restrict__ ri = indices + (size_t)row * NNZ;
    const float* __restrict__ rv = values  + (size_t)row * NNZ;
    const float4* __restrict__ w4 = (const float4*)w;

    float ax = 0.f, ay = 0.f, az = 0.f, aw = 0.f;
#pragma unroll 5
    for (int k = 0; k < NNZ / 8; ++k) {
        const int n = s + (k << 3);
        const int   u = ri[n];
        const float v = rv[n];
        const float4 wv = w4[(size_t)u * 8 + c];
        ax += v * wv.x; ay += v * wv.y; az += v * wv.z; aw += v * wv.w;
    }
#pragma unroll
    for (int m = 8; m <= 32; m <<= 1) {
        ax += __shfl_xor(ax, m); ay += __shfl_xor(ay, m);
        az += __shfl_xor(az, m); aw += __shfl_xor(aw, m);
    }
    if (s == 0) {
        const float4 b4 = ((const float4*)bias)[c];
        float4 o;
        o.x = ax + b4.x; o.y = ay + b4.y; o.z = az + b4.z; o.w = aw + b4.w;
        ((float4*)out)[(size_t)row * 8 + c] = o;
    }
}

extern "C" void kernel_launch(void* const* d_in, const int* in_sizes, int n_in,
                              void* d_out, int out_size, void* d_ws, size_t ws_size,
                              hipStream_t stream) {
    const int*   indices = (const int*)d_in[0];    // [16384, 200]
    const float* values  = (const float*)d_in[1];  // [16384, 200]
    const float* w       = (const float*)d_in[2];  // [81616, 32]
    const float* bias    = (const float*)d_in[3];  // [32]
    float* out = (float*)d_out;                    // [16384, 32]

    const int B = in_sizes[0] / NNZ;               // 16384
    const int grid = B / 4;                        // 4096 blocks, 4 rows each

    if (ws_size >= WBF_BYTES) {
        unsigned short* wb = (unsigned short*)d_ws;
        const int nelem = VOCAB * EMB;             // 2,611,712
        const int cgrid = (nelem / 8 + 255) / 256; // 1276
        convert_w_bf16<<<cgrid, 256, 0, stream>>>(w, wb, nelem);

        pe_pass<0><<<grid, THREADS, 0, stream>>>(indices, values, wb, bias, out);
        pe_pass<1><<<grid, THREADS, 0, stream>>>(indices, values, wb, bias, out);
    } else {
        pe_fp32_direct<<<grid, THREADS, 0, stream>>>(indices, values, w, bias, out);
    }
}